// Round 1
// baseline (1073.742 us; speedup 1.0000x reference)
//
#include <hip/hip_runtime.h>
#include <math.h>

// Plenoxels-style volume renderer.
// One 64-lane wave per ray; lane = sample index within a 64-sample chunk.
// 443 samples/ray -> 7 chunks. Transmittance cumprod = wave inclusive-product
// scan + scalar carry across chunks (matches reference cumprod incl. +1e-10).

namespace {
constexpr float kRadius   = 1.3f;
constexpr int   kRes      = 128;
constexpr float kStep     = 2.0f * 1.3f / 128.0f / 2.0f;   // 0.01015625
constexpr int   kNI       = 443;                           // N_INTRS - 1
constexpr int   kNRays    = 4096;
constexpr int   kChStride = kRes * kRes * kRes;            // 2097152
constexpr int   kChunks   = (kNI + 63) / 64;               // 7
}

// 8-corner trilerp of one channel plane p (weights/offsets from enclosing scope)
#define TRI8(p) (w000*(p)[o000] + w001*(p)[o001] + w010*(p)[o010] + w011*(p)[o011] \
               + w100*(p)[o100] + w101*(p)[o101] + w110*(p)[o110] + w111*(p)[o111])

__global__ __launch_bounds__(256)
void plenoxel_render(const float* __restrict__ rays_o,
                     const float* __restrict__ rays_d,
                     const float* __restrict__ grid,   // (28,128,128,128) f32
                     float* __restrict__ out)          // (4096,3) f32
{
    const int lane = threadIdx.x & 63;
    const int ray  = blockIdx.x * 4 + (threadIdx.x >> 6);

    const float ox = rays_o[3*ray+0], oy = rays_o[3*ray+1], oz = rays_o[3*ray+2];
    const float dx = rays_d[3*ray+0], dy = rays_d[3*ray+1], dz = rays_d[3*ray+2];

    // ray/box entry: start = max_axis min((R-o)/d, (-R-o)/d)  (inf-safe)
    const float sx = fminf(( kRadius - ox)/dx, (-kRadius - ox)/dx);
    const float sy = fminf(( kRadius - oy)/dy, (-kRadius - oy)/dy);
    const float sz = fminf(( kRadius - oz)/dz, (-kRadius - oz)/dz);
    const float start = fmaxf(sx, fmaxf(sy, sz));

    const float dnorm = sqrtf(dx*dx + dy*dy + dz*dz);

    // SH deg-2 basis of the ray direction (uniform across the wave)
    float shm[9];
    shm[0] =  0.28209479177387814f;
    shm[1] = -0.4886025119029199f * dy;
    shm[2] =  0.4886025119029199f * dz;
    shm[3] = -0.4886025119029199f * dx;
    shm[4] =  1.0925484305920792f * dx * dy;
    shm[5] = -1.0925484305920792f * dy * dz;
    shm[6] =  0.31539156525252005f * (2.0f*dz*dz - dx*dx - dy*dy);
    shm[7] = -1.0925484305920792f * dx * dz;
    shm[8] =  0.5462742152960396f * (dx*dx - dy*dy);

    float carry = 1.0f;                      // transmittance entering this chunk
    float accR = 0.f, accG = 0.f, accB = 0.f, accL = 0.f;

    for (int chunk = 0; chunk < kChunks; ++chunk) {
        const int k = chunk * 64 + lane;

        float alpha = 0.0f;
        float a     = 1.0f;                  // (1 - alpha + 1e-10) term
        float rp0 = 0.f, rp1 = 0.f, rp2 = 0.f;
        bool  inb = false;

        if (k < kNI) {
            const float t    = start + (float)k       * kStep;
            const float t1   = start + (float)(k + 1) * kStep;
            const float dist = (t1 - t) * dnorm;

            const float px = ox + t*dx;
            const float py = oy + t*dy;
            const float pz = oz + t*dz;
            inb = (px > -kRadius) && (px < kRadius) &&
                  (py > -kRadius) && (py < kRadius) &&
                  (pz > -kRadius) && (pz < kRadius);

            float sigma = 0.0f;
            if (inb) {
                // grid coords: clip((p/R + 1) * 0.5 * 127, 0, 127)
                const float cx = fminf(fmaxf((px*(1.0f/kRadius) + 1.0f)*0.5f*127.0f, 0.0f), 127.0f);
                const float cy = fminf(fmaxf((py*(1.0f/kRadius) + 1.0f)*0.5f*127.0f, 0.0f), 127.0f);
                const float cz = fminf(fmaxf((pz*(1.0f/kRadius) + 1.0f)*0.5f*127.0f, 0.0f), 127.0f);
                const float fx0 = floorf(cx), fy0 = floorf(cy), fz0 = floorf(cz);
                const float fx = cx - fx0, fy = cy - fy0, fz = cz - fz0;
                const int ix0 = (int)fx0, iy0 = (int)fy0, iz0 = (int)fz0;
                const int ix1 = min(ix0 + 1, 127);
                const int iy1 = min(iy0 + 1, 127);
                const int iz1 = min(iz0 + 1, 127);

                const float gx0 = 1.0f - fx, gy0 = 1.0f - fy, gz0 = 1.0f - fz;
                const float w000 = gz0*gy0*gx0, w001 = gz0*gy0*fx;
                const float w010 = gz0*fy *gx0, w011 = gz0*fy *fx;
                const float w100 = fz *gy0*gx0, w101 = fz *gy0*fx;
                const float w110 = fz *fy *gx0, w111 = fz *fy *fx;

                const int o000 = iz0*(kRes*kRes) + iy0*kRes + ix0;
                const int o001 = iz0*(kRes*kRes) + iy0*kRes + ix1;
                const int o010 = iz0*(kRes*kRes) + iy1*kRes + ix0;
                const int o011 = iz0*(kRes*kRes) + iy1*kRes + ix1;
                const int o100 = iz1*(kRes*kRes) + iy0*kRes + ix0;
                const int o101 = iz1*(kRes*kRes) + iy0*kRes + ix1;
                const int o110 = iz1*(kRes*kRes) + iy1*kRes + ix0;
                const int o111 = iz1*(kRes*kRes) + iy1*kRes + ix1;

                // 27 SH channels fused into 3 rgb dot-products, + 1 sigma channel
                #pragma unroll
                for (int kk = 0; kk < 9; ++kk) {
                    rp0 = fmaf(shm[kk], TRI8(grid + (kk     ) * kChStride), rp0);
                    rp1 = fmaf(shm[kk], TRI8(grid + (kk +  9) * kChStride), rp1);
                    rp2 = fmaf(shm[kk], TRI8(grid + (kk + 18) * kChStride), rp2);
                }
                sigma = fmaxf(TRI8(grid + 27 * kChStride), 0.0f);
            }
            alpha = 1.0f - expf(-sigma * dist);
            a     = 1.0f - alpha + 1e-10f;   // matches reference even when masked
        }

        // wave-level inclusive product scan of `a`
        float prod = a;
        #pragma unroll
        for (int off = 1; off < 64; off <<= 1) {
            const float y = __shfl_up(prod, off, 64);
            if (lane >= off) prod *= y;
        }
        float excl = __shfl_up(prod, 1, 64);
        if (lane == 0) excl = 1.0f;

        const float trans = carry * excl;
        const float w     = alpha * trans;    // abs_light

        if (inb) {
            const float sR = 1.0f / (1.0f + expf(-rp0));
            const float sG = 1.0f / (1.0f + expf(-rp1));
            const float sB = 1.0f / (1.0f + expf(-rp2));
            accR = fmaf(w, sR, accR);
            accG = fmaf(w, sG, accG);
            accB = fmaf(w, sB, accB);
        }
        accL += w;                            // masked lanes contribute w==0

        carry *= __shfl(prod, 63, 64);        // chunk-boundary carry
    }

    // wave reduction of the 4 accumulators
    #pragma unroll
    for (int off = 32; off > 0; off >>= 1) {
        accR += __shfl_down(accR, off, 64);
        accG += __shfl_down(accG, off, 64);
        accB += __shfl_down(accB, off, 64);
        accL += __shfl_down(accL, off, 64);
    }

    if (lane == 0) {
        const float bg = 1.0f - accL;
        out[3*ray + 0] = accR + bg;
        out[3*ray + 1] = accG + bg;
        out[3*ray + 2] = accB + bg;
    }
}

extern "C" void kernel_launch(void* const* d_in, const int* in_sizes, int n_in,
                              void* d_out, int out_size, void* d_ws, size_t ws_size,
                              hipStream_t stream) {
    const float* rays_o = (const float*)d_in[0];
    const float* rays_d = (const float*)d_in[1];
    const float* data   = (const float*)d_in[2];   // (1,28,128,128,128)
    float* out = (float*)d_out;

    hipLaunchKernelGGL(plenoxel_render,
                       dim3(kNRays / 4), dim3(256), 0, stream,
                       rays_o, rays_d, data, out);
}

// Round 2
// 588.918 us; speedup vs baseline: 1.8232x; 1.8232x over previous
//
#include <hip/hip_runtime.h>
#include <math.h>

// Plenoxels-style volume renderer, round 2.
// Key change: transpose grid (28,128^3) channel-major -> voxel-major
// (128^3, 28) into d_ws each call, so each trilerp corner is 7 contiguous
// float4 loads instead of 28 scattered dword gathers across 8MB strides.
// One 64-lane wave per ray; lane = sample index within a 64-sample chunk.

namespace {
constexpr float kRadius   = 1.3f;
constexpr int   kRes      = 128;
constexpr float kStep     = 2.0f * 1.3f / 128.0f / 2.0f;   // 0.01015625
constexpr int   kNI       = 443;                           // N_INTRS - 1
constexpr int   kNRays    = 4096;
constexpr int   kChStride = kRes * kRes * kRes;            // 2097152 voxels
constexpr int   kChunks   = (kNI + 63) / 64;               // 7
constexpr int   kCh       = 28;
}

// ---------------------------------------------------------------------------
// Transpose: grid[c][v] -> vox[v*28 + c].  One block = 256 voxels.
// LDS staged so both global reads and global writes are fully coalesced.
// Pad row stride to 257 to break the 28-way bank conflict on the read phase.
// ---------------------------------------------------------------------------
__global__ __launch_bounds__(256)
void transpose_grid(const float* __restrict__ grid, float* __restrict__ vox)
{
    __shared__ float lds[kCh * 257];
    const int tid  = threadIdx.x;
    const int base = blockIdx.x * 256;            // voxel base; 8192 blocks

    #pragma unroll
    for (int c = 0; c < kCh; ++c)
        lds[c * 257 + tid] = grid[c * kChStride + base + tid];
    __syncthreads();

    float* outp = vox + (size_t)base * kCh;       // 7168 contiguous floats
    #pragma unroll
    for (int i = 0; i < kCh; ++i) {
        const int f = i * 256 + tid;
        const int v = f / kCh;                    // magic-mul
        const int c = f - v * kCh;
        outp[f] = lds[c * 257 + v];
    }
}

// ---------------------------------------------------------------------------
// Render from voxel-major layout.
// ---------------------------------------------------------------------------
__global__ __launch_bounds__(256)
void plenoxel_render_vox(const float* __restrict__ rays_o,
                         const float* __restrict__ rays_d,
                         const float* __restrict__ vox,   // (128^3, 28) f32
                         float* __restrict__ out)         // (4096, 3) f32
{
    const int lane = threadIdx.x & 63;
    const int ray  = blockIdx.x * 4 + (threadIdx.x >> 6);

    const float ox = rays_o[3*ray+0], oy = rays_o[3*ray+1], oz = rays_o[3*ray+2];
    const float dx = rays_d[3*ray+0], dy = rays_d[3*ray+1], dz = rays_d[3*ray+2];

    const float sx = fminf(( kRadius - ox)/dx, (-kRadius - ox)/dx);
    const float sy = fminf(( kRadius - oy)/dy, (-kRadius - oy)/dy);
    const float sz = fminf(( kRadius - oz)/dz, (-kRadius - oz)/dz);
    const float start = fmaxf(sx, fmaxf(sy, sz));

    const float dnorm = sqrtf(dx*dx + dy*dy + dz*dz);

    float shm[9];
    shm[0] =  0.28209479177387814f;
    shm[1] = -0.4886025119029199f * dy;
    shm[2] =  0.4886025119029199f * dz;
    shm[3] = -0.4886025119029199f * dx;
    shm[4] =  1.0925484305920792f * dx * dy;
    shm[5] = -1.0925484305920792f * dy * dz;
    shm[6] =  0.31539156525252005f * (2.0f*dz*dz - dx*dx - dy*dy);
    shm[7] = -1.0925484305920792f * dx * dz;
    shm[8] =  0.5462742152960396f * (dx*dx - dy*dy);

    float carry = 1.0f;
    float accR = 0.f, accG = 0.f, accB = 0.f, accL = 0.f;

    for (int chunk = 0; chunk < kChunks; ++chunk) {
        const int k = chunk * 64 + lane;

        float alpha = 0.0f;
        float a     = 1.0f;
        float rp0 = 0.f, rp1 = 0.f, rp2 = 0.f;
        bool  inb = false;

        if (k < kNI) {
            const float t    = start + (float)k * kStep;
            const float dist = kStep * dnorm;

            const float px = ox + t*dx;
            const float py = oy + t*dy;
            const float pz = oz + t*dz;
            inb = (px > -kRadius) && (px < kRadius) &&
                  (py > -kRadius) && (py < kRadius) &&
                  (pz > -kRadius) && (pz < kRadius);

            float sig = 0.0f;
            if (inb) {
                const float cx = fminf(fmaxf((px*(1.0f/kRadius) + 1.0f)*0.5f*127.0f, 0.0f), 127.0f);
                const float cy = fminf(fmaxf((py*(1.0f/kRadius) + 1.0f)*0.5f*127.0f, 0.0f), 127.0f);
                const float cz = fminf(fmaxf((pz*(1.0f/kRadius) + 1.0f)*0.5f*127.0f, 0.0f), 127.0f);
                const float fx0 = floorf(cx), fy0 = floorf(cy), fz0 = floorf(cz);
                const float fx = cx - fx0, fy = cy - fy0, fz = cz - fz0;
                const int ix0 = (int)fx0, iy0 = (int)fy0, iz0 = (int)fz0;
                const int ix1 = min(ix0 + 1, 127);
                const int iy1 = min(iy0 + 1, 127);
                const int iz1 = min(iz0 + 1, 127);

                const float gx0 = 1.0f - fx, gy0 = 1.0f - fy, gz0 = 1.0f - fz;

                const int offs[8] = {
                    iz0*(kRes*kRes) + iy0*kRes + ix0,
                    iz0*(kRes*kRes) + iy0*kRes + ix1,
                    iz0*(kRes*kRes) + iy1*kRes + ix0,
                    iz0*(kRes*kRes) + iy1*kRes + ix1,
                    iz1*(kRes*kRes) + iy0*kRes + ix0,
                    iz1*(kRes*kRes) + iy0*kRes + ix1,
                    iz1*(kRes*kRes) + iy1*kRes + ix0,
                    iz1*(kRes*kRes) + iy1*kRes + ix1 };
                const float cw[8] = {
                    gz0*gy0*gx0, gz0*gy0*fx, gz0*fy*gx0, gz0*fy*fx,
                    fz *gy0*gx0, fz *gy0*fx, fz *fy*gx0, fz *fy*fx };

                #pragma unroll
                for (int cn = 0; cn < 8; ++cn) {
                    const float4* p = reinterpret_cast<const float4*>(vox + offs[cn] * kCh);
                    const float4 q0 = p[0], q1 = p[1], q2 = p[2], q3 = p[3];
                    const float4 q4 = p[4], q5 = p[5], q6 = p[6];

                    float r = shm[0]*q0.x + shm[1]*q0.y + shm[2]*q0.z + shm[3]*q0.w
                            + shm[4]*q1.x + shm[5]*q1.y + shm[6]*q1.z + shm[7]*q1.w
                            + shm[8]*q2.x;
                    float g = shm[0]*q2.y + shm[1]*q2.z + shm[2]*q2.w + shm[3]*q3.x
                            + shm[4]*q3.y + shm[5]*q3.z + shm[6]*q3.w + shm[7]*q4.x
                            + shm[8]*q4.y;
                    float b = shm[0]*q4.z + shm[1]*q4.w + shm[2]*q5.x + shm[3]*q5.y
                            + shm[4]*q5.z + shm[5]*q5.w + shm[6]*q6.x + shm[7]*q6.y
                            + shm[8]*q6.z;

                    const float wc = cw[cn];
                    rp0 = fmaf(wc, r, rp0);
                    rp1 = fmaf(wc, g, rp1);
                    rp2 = fmaf(wc, b, rp2);
                    sig = fmaf(wc, q6.w, sig);
                }
                sig = fmaxf(sig, 0.0f);
            }
            alpha = 1.0f - expf(-sig * dist);
            a     = 1.0f - alpha + 1e-10f;
        }

        // wave inclusive-product scan of a
        float prod = a;
        #pragma unroll
        for (int off = 1; off < 64; off <<= 1) {
            const float y = __shfl_up(prod, off, 64);
            if (lane >= off) prod *= y;
        }
        float excl = __shfl_up(prod, 1, 64);
        if (lane == 0) excl = 1.0f;

        const float trans = carry * excl;
        const float w     = alpha * trans;

        if (inb) {
            accR = fmaf(w, 1.0f / (1.0f + expf(-rp0)), accR);
            accG = fmaf(w, 1.0f / (1.0f + expf(-rp1)), accG);
            accB = fmaf(w, 1.0f / (1.0f + expf(-rp2)), accB);
        }
        accL += w;

        carry *= __shfl(prod, 63, 64);
    }

    #pragma unroll
    for (int off = 32; off > 0; off >>= 1) {
        accR += __shfl_down(accR, off, 64);
        accG += __shfl_down(accG, off, 64);
        accB += __shfl_down(accB, off, 64);
        accL += __shfl_down(accL, off, 64);
    }

    if (lane == 0) {
        const float bg = 1.0f - accL;
        out[3*ray + 0] = accR + bg;
        out[3*ray + 1] = accG + bg;
        out[3*ray + 2] = accB + bg;
    }
}

// ---------------------------------------------------------------------------
// Fallback: direct channel-major render (round-1 kernel) if ws too small.
// ---------------------------------------------------------------------------
#define TRI8(p) (w000*(p)[o000] + w001*(p)[o001] + w010*(p)[o010] + w011*(p)[o011] \
               + w100*(p)[o100] + w101*(p)[o101] + w110*(p)[o110] + w111*(p)[o111])

__global__ __launch_bounds__(256)
void plenoxel_render_direct(const float* __restrict__ rays_o,
                            const float* __restrict__ rays_d,
                            const float* __restrict__ grid,
                            float* __restrict__ out)
{
    const int lane = threadIdx.x & 63;
    const int ray  = blockIdx.x * 4 + (threadIdx.x >> 6);

    const float ox = rays_o[3*ray+0], oy = rays_o[3*ray+1], oz = rays_o[3*ray+2];
    const float dx = rays_d[3*ray+0], dy = rays_d[3*ray+1], dz = rays_d[3*ray+2];

    const float sx = fminf(( kRadius - ox)/dx, (-kRadius - ox)/dx);
    const float sy = fminf(( kRadius - oy)/dy, (-kRadius - oy)/dy);
    const float sz = fminf(( kRadius - oz)/dz, (-kRadius - oz)/dz);
    const float start = fmaxf(sx, fmaxf(sy, sz));
    const float dnorm = sqrtf(dx*dx + dy*dy + dz*dz);

    float shm[9];
    shm[0] =  0.28209479177387814f;
    shm[1] = -0.4886025119029199f * dy;
    shm[2] =  0.4886025119029199f * dz;
    shm[3] = -0.4886025119029199f * dx;
    shm[4] =  1.0925484305920792f * dx * dy;
    shm[5] = -1.0925484305920792f * dy * dz;
    shm[6] =  0.31539156525252005f * (2.0f*dz*dz - dx*dx - dy*dy);
    shm[7] = -1.0925484305920792f * dx * dz;
    shm[8] =  0.5462742152960396f * (dx*dx - dy*dy);

    float carry = 1.0f;
    float accR = 0.f, accG = 0.f, accB = 0.f, accL = 0.f;

    for (int chunk = 0; chunk < kChunks; ++chunk) {
        const int k = chunk * 64 + lane;
        float alpha = 0.0f, a = 1.0f;
        float rp0 = 0.f, rp1 = 0.f, rp2 = 0.f;
        bool inb = false;

        if (k < kNI) {
            const float t = start + (float)k * kStep;
            const float dist = kStep * dnorm;
            const float px = ox + t*dx, py = oy + t*dy, pz = oz + t*dz;
            inb = (px > -kRadius) && (px < kRadius) &&
                  (py > -kRadius) && (py < kRadius) &&
                  (pz > -kRadius) && (pz < kRadius);
            float sigma = 0.0f;
            if (inb) {
                const float cx = fminf(fmaxf((px*(1.0f/kRadius) + 1.0f)*0.5f*127.0f, 0.0f), 127.0f);
                const float cy = fminf(fmaxf((py*(1.0f/kRadius) + 1.0f)*0.5f*127.0f, 0.0f), 127.0f);
                const float cz = fminf(fmaxf((pz*(1.0f/kRadius) + 1.0f)*0.5f*127.0f, 0.0f), 127.0f);
                const float fx0 = floorf(cx), fy0 = floorf(cy), fz0 = floorf(cz);
                const float fx = cx - fx0, fy = cy - fy0, fz = cz - fz0;
                const int ix0 = (int)fx0, iy0 = (int)fy0, iz0 = (int)fz0;
                const int ix1 = min(ix0 + 1, 127);
                const int iy1 = min(iy0 + 1, 127);
                const int iz1 = min(iz0 + 1, 127);
                const float gx0 = 1.0f - fx, gy0 = 1.0f - fy, gz0 = 1.0f - fz;
                const float w000 = gz0*gy0*gx0, w001 = gz0*gy0*fx;
                const float w010 = gz0*fy *gx0, w011 = gz0*fy *fx;
                const float w100 = fz *gy0*gx0, w101 = fz *gy0*fx;
                const float w110 = fz *fy *gx0, w111 = fz *fy *fx;
                const int o000 = iz0*(kRes*kRes) + iy0*kRes + ix0;
                const int o001 = iz0*(kRes*kRes) + iy0*kRes + ix1;
                const int o010 = iz0*(kRes*kRes) + iy1*kRes + ix0;
                const int o011 = iz0*(kRes*kRes) + iy1*kRes + ix1;
                const int o100 = iz1*(kRes*kRes) + iy0*kRes + ix0;
                const int o101 = iz1*(kRes*kRes) + iy0*kRes + ix1;
                const int o110 = iz1*(kRes*kRes) + iy1*kRes + ix0;
                const int o111 = iz1*(kRes*kRes) + iy1*kRes + ix1;
                #pragma unroll
                for (int kk = 0; kk < 9; ++kk) {
                    rp0 = fmaf(shm[kk], TRI8(grid + (kk     ) * kChStride), rp0);
                    rp1 = fmaf(shm[kk], TRI8(grid + (kk +  9) * kChStride), rp1);
                    rp2 = fmaf(shm[kk], TRI8(grid + (kk + 18) * kChStride), rp2);
                }
                sigma = fmaxf(TRI8(grid + 27 * kChStride), 0.0f);
            }
            alpha = 1.0f - expf(-sigma * dist);
            a     = 1.0f - alpha + 1e-10f;
        }

        float prod = a;
        #pragma unroll
        for (int off = 1; off < 64; off <<= 1) {
            const float y = __shfl_up(prod, off, 64);
            if (lane >= off) prod *= y;
        }
        float excl = __shfl_up(prod, 1, 64);
        if (lane == 0) excl = 1.0f;
        const float trans = carry * excl;
        const float w = alpha * trans;
        if (inb) {
            accR = fmaf(w, 1.0f / (1.0f + expf(-rp0)), accR);
            accG = fmaf(w, 1.0f / (1.0f + expf(-rp1)), accG);
            accB = fmaf(w, 1.0f / (1.0f + expf(-rp2)), accB);
        }
        accL += w;
        carry *= __shfl(prod, 63, 64);
    }

    #pragma unroll
    for (int off = 32; off > 0; off >>= 1) {
        accR += __shfl_down(accR, off, 64);
        accG += __shfl_down(accG, off, 64);
        accB += __shfl_down(accB, off, 64);
        accL += __shfl_down(accL, off, 64);
    }

    if (lane == 0) {
        const float bg = 1.0f - accL;
        out[3*ray + 0] = accR + bg;
        out[3*ray + 1] = accG + bg;
        out[3*ray + 2] = accB + bg;
    }
}

extern "C" void kernel_launch(void* const* d_in, const int* in_sizes, int n_in,
                              void* d_out, int out_size, void* d_ws, size_t ws_size,
                              hipStream_t stream) {
    const float* rays_o = (const float*)d_in[0];
    const float* rays_d = (const float*)d_in[1];
    const float* data   = (const float*)d_in[2];   // (1,28,128,128,128)
    float* out = (float*)d_out;

    const size_t need = (size_t)kChStride * kCh * sizeof(float);   // 235 MB
    if (ws_size >= need) {
        float* vox = (float*)d_ws;
        hipLaunchKernelGGL(transpose_grid,
                           dim3(kChStride / 256), dim3(256), 0, stream,
                           data, vox);
        hipLaunchKernelGGL(plenoxel_render_vox,
                           dim3(kNRays / 4), dim3(256), 0, stream,
                           rays_o, rays_d, vox, out);
    } else {
        hipLaunchKernelGGL(plenoxel_render_direct,
                           dim3(kNRays / 4), dim3(256), 0, stream,
                           rays_o, rays_d, data, out);
    }
}

// Round 3
// 435.620 us; speedup vs baseline: 2.4649x; 1.3519x over previous
//
#include <hip/hip_runtime.h>
#include <math.h>

// Plenoxels renderer, round 3.
//  - grid converted each call to fp16 voxel-major records padded to 64B
//    (28 halves + 4 pad) -> one cacheline per voxel, 134MB (fits L3).
//  - render parallelized over (ray, chunk): cumprod carry is linear in
//    incoming transmittance, so chunks are independent up to a scalar;
//    a tiny combine kernel stitches the 7 chunk partials per ray.

typedef _Float16 h8 __attribute__((ext_vector_type(8)));

namespace {
constexpr float kRadius   = 1.3f;
constexpr int   kRes      = 128;
constexpr float kStep     = 2.0f * 1.3f / 128.0f / 2.0f;   // 0.01015625
constexpr int   kNI       = 443;                           // N_INTRS - 1
constexpr int   kNRays    = 4096;
constexpr int   kChStride = kRes * kRes * kRes;            // 2097152 voxels
constexpr int   kChunks   = 7;                             // ceil(443/64)
constexpr int   kCh       = 28;
constexpr int   kVoxPad   = 32;                            // halves per record (64B)
constexpr size_t kVoxBytes = (size_t)kChStride * kVoxPad * sizeof(_Float16); // 2^27
}

// ---------------------------------------------------------------------------
// Convert grid[c][v] (f32, channel-major) -> vox[v] = 32 halves (64B record).
// One lane per voxel: reads coalesced per channel, writes 4x16B.
// ---------------------------------------------------------------------------
__global__ __launch_bounds__(256)
void convert_grid(const float* __restrict__ grid, _Float16* __restrict__ vox)
{
    const int v = blockIdx.x * 256 + threadIdx.x;          // 8192 blocks
    h8 o[4];
    #pragma unroll
    for (int c = 0; c < kCh; ++c)
        o[c >> 3][c & 7] = (_Float16)grid[c * kChStride + v];
    o[3][4] = o[3][5] = o[3][6] = o[3][7] = (_Float16)0.f;

    h8* dst = (h8*)(vox + (size_t)v * kVoxPad);
    dst[0] = o[0]; dst[1] = o[1]; dst[2] = o[2]; dst[3] = o[3];
}

// ---------------------------------------------------------------------------
// Render one 64-sample chunk of one ray per wave.
// Emits per-(ray,chunk): S_R,S_G,S_B,S_L (sums assuming unit incoming
// transmittance) and P (product of (1-alpha+1e-10) over the chunk).
// ---------------------------------------------------------------------------
__global__ __launch_bounds__(256)
void render_chunks(const float* __restrict__ rays_o,
                   const float* __restrict__ rays_d,
                   const _Float16* __restrict__ vox,
                   float* __restrict__ partials)           // (4096,7,5)
{
    const int lane  = threadIdx.x & 63;
    const int W     = blockIdx.x * 4 + (threadIdx.x >> 6); // 28672 waves
    const int ray   = W / 7;
    const int chunk = W - ray * 7;

    const float ox = rays_o[3*ray+0], oy = rays_o[3*ray+1], oz = rays_o[3*ray+2];
    const float dx = rays_d[3*ray+0], dy = rays_d[3*ray+1], dz = rays_d[3*ray+2];

    const float sx = fminf(( kRadius - ox)/dx, (-kRadius - ox)/dx);
    const float sy = fminf(( kRadius - oy)/dy, (-kRadius - oy)/dy);
    const float sz = fminf(( kRadius - oz)/dz, (-kRadius - oz)/dz);
    const float start = fmaxf(sx, fmaxf(sy, sz));
    const float dnorm = sqrtf(dx*dx + dy*dy + dz*dz);
    const float dist  = kStep * dnorm;

    float shm[9];
    shm[0] =  0.28209479177387814f;
    shm[1] = -0.4886025119029199f * dy;
    shm[2] =  0.4886025119029199f * dz;
    shm[3] = -0.4886025119029199f * dx;
    shm[4] =  1.0925484305920792f * dx * dy;
    shm[5] = -1.0925484305920792f * dy * dz;
    shm[6] =  0.31539156525252005f * (2.0f*dz*dz - dx*dx - dy*dy);
    shm[7] = -1.0925484305920792f * dx * dz;
    shm[8] =  0.5462742152960396f * (dx*dx - dy*dy);

    const int k = chunk * 64 + lane;

    float alpha = 0.0f;
    float a     = 1.0f;
    float rp0 = 0.f, rp1 = 0.f, rp2 = 0.f;
    bool  inb = false;

    if (k < kNI) {
        const float t  = start + (float)k * kStep;
        const float px = ox + t*dx;
        const float py = oy + t*dy;
        const float pz = oz + t*dz;
        inb = (px > -kRadius) && (px < kRadius) &&
              (py > -kRadius) && (py < kRadius) &&
              (pz > -kRadius) && (pz < kRadius);

        float sig = 0.0f;
        if (inb) {
            const float cx = fminf(fmaxf((px*(1.0f/kRadius) + 1.0f)*0.5f*127.0f, 0.0f), 127.0f);
            const float cy = fminf(fmaxf((py*(1.0f/kRadius) + 1.0f)*0.5f*127.0f, 0.0f), 127.0f);
            const float cz = fminf(fmaxf((pz*(1.0f/kRadius) + 1.0f)*0.5f*127.0f, 0.0f), 127.0f);
            const float fx0 = floorf(cx), fy0 = floorf(cy), fz0 = floorf(cz);
            const float fx = cx - fx0, fy = cy - fy0, fz = cz - fz0;
            const int ix0 = (int)fx0, iy0 = (int)fy0, iz0 = (int)fz0;
            const int ix1 = min(ix0 + 1, 127);
            const int iy1 = min(iy0 + 1, 127);
            const int iz1 = min(iz0 + 1, 127);

            const float gx0 = 1.0f - fx, gy0 = 1.0f - fy, gz0 = 1.0f - fz;

            const int offs[8] = {
                iz0*(kRes*kRes) + iy0*kRes + ix0,
                iz0*(kRes*kRes) + iy0*kRes + ix1,
                iz0*(kRes*kRes) + iy1*kRes + ix0,
                iz0*(kRes*kRes) + iy1*kRes + ix1,
                iz1*(kRes*kRes) + iy0*kRes + ix0,
                iz1*(kRes*kRes) + iy0*kRes + ix1,
                iz1*(kRes*kRes) + iy1*kRes + ix0,
                iz1*(kRes*kRes) + iy1*kRes + ix1 };
            const float cw[8] = {
                gz0*gy0*gx0, gz0*gy0*fx, gz0*fy*gx0, gz0*fy*fx,
                fz *gy0*gx0, fz *gy0*fx, fz *fy*gx0, fz *fy*fx };

            #pragma unroll
            for (int cn = 0; cn < 8; ++cn) {
                const h8* vp = (const h8*)(vox + (size_t)offs[cn] * kVoxPad);
                const h8 q0 = vp[0], q1 = vp[1], q2 = vp[2], q3 = vp[3];

                float f[28];
                #pragma unroll
                for (int i = 0; i < 8; ++i) f[i]      = (float)q0[i];
                #pragma unroll
                for (int i = 0; i < 8; ++i) f[8 + i]  = (float)q1[i];
                #pragma unroll
                for (int i = 0; i < 8; ++i) f[16 + i] = (float)q2[i];
                #pragma unroll
                for (int i = 0; i < 4; ++i) f[24 + i] = (float)q3[i];

                float r = 0.f, g = 0.f, b = 0.f;
                #pragma unroll
                for (int j = 0; j < 9; ++j) {
                    r = fmaf(shm[j], f[j],      r);
                    g = fmaf(shm[j], f[9 + j],  g);
                    b = fmaf(shm[j], f[18 + j], b);
                }
                const float wc = cw[cn];
                rp0 = fmaf(wc, r, rp0);
                rp1 = fmaf(wc, g, rp1);
                rp2 = fmaf(wc, b, rp2);
                sig = fmaf(wc, f[27], sig);
            }
            sig = fmaxf(sig, 0.0f);
        }
        alpha = 1.0f - expf(-sig * dist);
        a     = 1.0f - alpha + 1e-10f;
    }

    // wave inclusive-product scan of a (within-chunk transmittance)
    float prod = a;
    #pragma unroll
    for (int off = 1; off < 64; off <<= 1) {
        const float y = __shfl_up(prod, off, 64);
        if (lane >= off) prod *= y;
    }
    float excl = __shfl_up(prod, 1, 64);
    if (lane == 0) excl = 1.0f;

    const float w = alpha * excl;      // abs_light assuming unit carry

    float sR = 0.f, sG = 0.f, sB = 0.f;
    if (inb) {
        sR = w * (1.0f / (1.0f + expf(-rp0)));
        sG = w * (1.0f / (1.0f + expf(-rp1)));
        sB = w * (1.0f / (1.0f + expf(-rp2)));
    }
    float sL = w;

    const float P = __shfl(prod, 63, 64);   // chunk total product

    #pragma unroll
    for (int off = 32; off > 0; off >>= 1) {
        sR += __shfl_down(sR, off, 64);
        sG += __shfl_down(sG, off, 64);
        sB += __shfl_down(sB, off, 64);
        sL += __shfl_down(sL, off, 64);
    }

    if (lane == 0) {
        float* p = partials + (size_t)(ray * 7 + chunk) * 5;
        p[0] = sR; p[1] = sG; p[2] = sB; p[3] = sL; p[4] = P;
    }
}

// ---------------------------------------------------------------------------
// Stitch chunk partials: acc += carry * S_c ; carry *= P_c.
// ---------------------------------------------------------------------------
__global__ __launch_bounds__(256)
void combine_chunks(const float* __restrict__ partials, float* __restrict__ out)
{
    const int r = blockIdx.x * 256 + threadIdx.x;          // 16 blocks
    const float* p = partials + (size_t)r * (kChunks * 5);

    float carry = 1.0f, aR = 0.f, aG = 0.f, aB = 0.f, aL = 0.f;
    #pragma unroll
    for (int c = 0; c < kChunks; ++c) {
        aR = fmaf(carry, p[c*5 + 0], aR);
        aG = fmaf(carry, p[c*5 + 1], aG);
        aB = fmaf(carry, p[c*5 + 2], aB);
        aL = fmaf(carry, p[c*5 + 3], aL);
        carry *= p[c*5 + 4];
    }
    const float bg = 1.0f - aL;
    out[3*r + 0] = aR + bg;
    out[3*r + 1] = aG + bg;
    out[3*r + 2] = aB + bg;
}

// ---------------------------------------------------------------------------
// Fallback: direct channel-major render (round-1 style) if ws too small.
// ---------------------------------------------------------------------------
#define TRI8(p) (w000*(p)[o000] + w001*(p)[o001] + w010*(p)[o010] + w011*(p)[o011] \
               + w100*(p)[o100] + w101*(p)[o101] + w110*(p)[o110] + w111*(p)[o111])

__global__ __launch_bounds__(256)
void plenoxel_render_direct(const float* __restrict__ rays_o,
                            const float* __restrict__ rays_d,
                            const float* __restrict__ grid,
                            float* __restrict__ out)
{
    const int lane = threadIdx.x & 63;
    const int ray  = blockIdx.x * 4 + (threadIdx.x >> 6);

    const float ox = rays_o[3*ray+0], oy = rays_o[3*ray+1], oz = rays_o[3*ray+2];
    const float dx = rays_d[3*ray+0], dy = rays_d[3*ray+1], dz = rays_d[3*ray+2];

    const float sx = fminf(( kRadius - ox)/dx, (-kRadius - ox)/dx);
    const float sy = fminf(( kRadius - oy)/dy, (-kRadius - oy)/dy);
    const float sz = fminf(( kRadius - oz)/dz, (-kRadius - oz)/dz);
    const float start = fmaxf(sx, fmaxf(sy, sz));
    const float dnorm = sqrtf(dx*dx + dy*dy + dz*dz);

    float shm[9];
    shm[0] =  0.28209479177387814f;
    shm[1] = -0.4886025119029199f * dy;
    shm[2] =  0.4886025119029199f * dz;
    shm[3] = -0.4886025119029199f * dx;
    shm[4] =  1.0925484305920792f * dx * dy;
    shm[5] = -1.0925484305920792f * dy * dz;
    shm[6] =  0.31539156525252005f * (2.0f*dz*dz - dx*dx - dy*dy);
    shm[7] = -1.0925484305920792f * dx * dz;
    shm[8] =  0.5462742152960396f * (dx*dx - dy*dy);

    float carry = 1.0f;
    float accR = 0.f, accG = 0.f, accB = 0.f, accL = 0.f;

    for (int chunk = 0; chunk < kChunks; ++chunk) {
        const int k = chunk * 64 + lane;
        float alpha = 0.0f, a = 1.0f;
        float rp0 = 0.f, rp1 = 0.f, rp2 = 0.f;
        bool inb = false;

        if (k < kNI) {
            const float t = start + (float)k * kStep;
            const float dist = kStep * dnorm;
            const float px = ox + t*dx, py = oy + t*dy, pz = oz + t*dz;
            inb = (px > -kRadius) && (px < kRadius) &&
                  (py > -kRadius) && (py < kRadius) &&
                  (pz > -kRadius) && (pz < kRadius);
            float sigma = 0.0f;
            if (inb) {
                const float cx = fminf(fmaxf((px*(1.0f/kRadius) + 1.0f)*0.5f*127.0f, 0.0f), 127.0f);
                const float cy = fminf(fmaxf((py*(1.0f/kRadius) + 1.0f)*0.5f*127.0f, 0.0f), 127.0f);
                const float cz = fminf(fmaxf((pz*(1.0f/kRadius) + 1.0f)*0.5f*127.0f, 0.0f), 127.0f);
                const float fx0 = floorf(cx), fy0 = floorf(cy), fz0 = floorf(cz);
                const float fx = cx - fx0, fy = cy - fy0, fz = cz - fz0;
                const int ix0 = (int)fx0, iy0 = (int)fy0, iz0 = (int)fz0;
                const int ix1 = min(ix0 + 1, 127);
                const int iy1 = min(iy0 + 1, 127);
                const int iz1 = min(iz0 + 1, 127);
                const float gx0 = 1.0f - fx, gy0 = 1.0f - fy, gz0 = 1.0f - fz;
                const float w000 = gz0*gy0*gx0, w001 = gz0*gy0*fx;
                const float w010 = gz0*fy *gx0, w011 = gz0*fy *fx;
                const float w100 = fz *gy0*gx0, w101 = fz *gy0*fx;
                const float w110 = fz *fy *gx0, w111 = fz *fy *fx;
                const int o000 = iz0*(kRes*kRes) + iy0*kRes + ix0;
                const int o001 = iz0*(kRes*kRes) + iy0*kRes + ix1;
                const int o010 = iz0*(kRes*kRes) + iy1*kRes + ix0;
                const int o011 = iz0*(kRes*kRes) + iy1*kRes + ix1;
                const int o100 = iz1*(kRes*kRes) + iy0*kRes + ix0;
                const int o101 = iz1*(kRes*kRes) + iy0*kRes + ix1;
                const int o110 = iz1*(kRes*kRes) + iy1*kRes + ix0;
                const int o111 = iz1*(kRes*kRes) + iy1*kRes + ix1;
                #pragma unroll
                for (int kk = 0; kk < 9; ++kk) {
                    rp0 = fmaf(shm[kk], TRI8(grid + (kk     ) * kChStride), rp0);
                    rp1 = fmaf(shm[kk], TRI8(grid + (kk +  9) * kChStride), rp1);
                    rp2 = fmaf(shm[kk], TRI8(grid + (kk + 18) * kChStride), rp2);
                }
                sigma = fmaxf(TRI8(grid + 27 * kChStride), 0.0f);
            }
            alpha = 1.0f - expf(-sigma * dist);
            a     = 1.0f - alpha + 1e-10f;
        }

        float prod = a;
        #pragma unroll
        for (int off = 1; off < 64; off <<= 1) {
            const float y = __shfl_up(prod, off, 64);
            if (lane >= off) prod *= y;
        }
        float excl = __shfl_up(prod, 1, 64);
        if (lane == 0) excl = 1.0f;
        const float trans = carry * excl;
        const float w = alpha * trans;
        if (inb) {
            accR = fmaf(w, 1.0f / (1.0f + expf(-rp0)), accR);
            accG = fmaf(w, 1.0f / (1.0f + expf(-rp1)), accG);
            accB = fmaf(w, 1.0f / (1.0f + expf(-rp2)), accB);
        }
        accL += w;
        carry *= __shfl(prod, 63, 64);
    }

    #pragma unroll
    for (int off = 32; off > 0; off >>= 1) {
        accR += __shfl_down(accR, off, 64);
        accG += __shfl_down(accG, off, 64);
        accB += __shfl_down(accB, off, 64);
        accL += __shfl_down(accL, off, 64);
    }

    if (lane == 0) {
        const float bg = 1.0f - accL;
        out[3*ray + 0] = accR + bg;
        out[3*ray + 1] = accG + bg;
        out[3*ray + 2] = accB + bg;
    }
}

extern "C" void kernel_launch(void* const* d_in, const int* in_sizes, int n_in,
                              void* d_out, int out_size, void* d_ws, size_t ws_size,
                              hipStream_t stream) {
    const float* rays_o = (const float*)d_in[0];
    const float* rays_d = (const float*)d_in[1];
    const float* data   = (const float*)d_in[2];   // (1,28,128,128,128)
    float* out = (float*)d_out;

    const size_t partBytes = (size_t)kNRays * kChunks * 5 * sizeof(float);
    const size_t need = kVoxBytes + partBytes;     // ~134.8 MB

    if (ws_size >= need) {
        _Float16* vox = (_Float16*)d_ws;
        float* partials = (float*)((char*)d_ws + kVoxBytes);

        hipLaunchKernelGGL(convert_grid,
                           dim3(kChStride / 256), dim3(256), 0, stream,
                           data, vox);
        hipLaunchKernelGGL(render_chunks,
                           dim3(kNRays * kChunks / 4), dim3(256), 0, stream,
                           rays_o, rays_d, vox, partials);
        hipLaunchKernelGGL(combine_chunks,
                           dim3(kNRays / 256), dim3(256), 0, stream,
                           partials, out);
    } else {
        hipLaunchKernelGGL(plenoxel_render_direct,
                           dim3(kNRays / 4), dim3(256), 0, stream,
                           rays_o, rays_d, data, out);
    }
}

// Round 4
// 403.550 us; speedup vs baseline: 2.6607x; 1.0795x over previous
//
#include <hip/hip_runtime.h>
#include <math.h>

// Plenoxels renderer, round 4.
//  - fp16 voxel-major records padded to 64B (one cacheline/voxel), 134MB.
//  - render: 2 samples per lane (k, k+64) within 128-sample chunks ->
//    2x memory-level parallelism, lane spacing still 0.5 voxel for L1 reuse.
//  - convert uses nontemporal loads so the read-once f32 grid doesn't evict
//    the freshly written vox array from L2/L3.

typedef _Float16 h8 __attribute__((ext_vector_type(8)));

namespace {
constexpr float kRadius   = 1.3f;
constexpr int   kRes      = 128;
constexpr float kStep     = 2.0f * 1.3f / 128.0f / 2.0f;   // 0.01015625
constexpr int   kNI       = 443;                           // N_INTRS - 1
constexpr int   kNRays    = 4096;
constexpr int   kChStride = kRes * kRes * kRes;            // 2097152 voxels
constexpr int   kCh       = 28;
constexpr int   kVoxPad   = 32;                            // halves per 64B record
constexpr size_t kVoxBytes = (size_t)kChStride * kVoxPad * sizeof(_Float16);
constexpr int   kChunks4  = 4;                             // 128-sample chunks
constexpr int   kChunks7  = 7;                             // fallback: 64-sample
}

// ---------------------------------------------------------------------------
// Convert grid[c][v] (f32 channel-major) -> vox[v] = 32 halves (64B record).
// Nontemporal reads: grid is read once, keep L2/L3 for vox.
// ---------------------------------------------------------------------------
__global__ __launch_bounds__(256)
void convert_grid(const float* __restrict__ grid, _Float16* __restrict__ vox)
{
    const int v = blockIdx.x * 256 + threadIdx.x;          // 8192 blocks
    h8 o[4];
    #pragma unroll
    for (int c = 0; c < kCh; ++c)
        o[c >> 3][c & 7] = (_Float16)__builtin_nontemporal_load(grid + (size_t)c * kChStride + v);
    o[3][4] = o[3][5] = o[3][6] = o[3][7] = (_Float16)0.f;

    h8* dst = (h8*)(vox + (size_t)v * kVoxPad);
    dst[0] = o[0]; dst[1] = o[1]; dst[2] = o[2]; dst[3] = o[3];
}

// ---------------------------------------------------------------------------
// Per-sample evaluation: trilerped sigma->alpha and SH-dot rgb logits.
// ---------------------------------------------------------------------------
struct Sample {
    float alpha;   // 1 - exp(-sigma*dist)
    float a;       // 1 - alpha + 1e-10
    float rp0, rp1, rp2;
    bool  inb;
};

__device__ __forceinline__ Sample eval_sample(
    int k, float start, float ox, float oy, float oz,
    float dx, float dy, float dz, float dist,
    const float* __restrict__ shm, const _Float16* __restrict__ vox)
{
    Sample s;
    s.alpha = 0.f; s.a = 1.f; s.rp0 = s.rp1 = s.rp2 = 0.f; s.inb = false;
    if (k >= kNI) return s;

    const float t  = start + (float)k * kStep;
    const float px = ox + t*dx;
    const float py = oy + t*dy;
    const float pz = oz + t*dz;
    s.inb = (px > -kRadius) && (px < kRadius) &&
            (py > -kRadius) && (py < kRadius) &&
            (pz > -kRadius) && (pz < kRadius);

    float sig = 0.0f;
    if (s.inb) {
        const float cx = fminf(fmaxf((px*(1.0f/kRadius) + 1.0f)*0.5f*127.0f, 0.0f), 127.0f);
        const float cy = fminf(fmaxf((py*(1.0f/kRadius) + 1.0f)*0.5f*127.0f, 0.0f), 127.0f);
        const float cz = fminf(fmaxf((pz*(1.0f/kRadius) + 1.0f)*0.5f*127.0f, 0.0f), 127.0f);
        const float fx0 = floorf(cx), fy0 = floorf(cy), fz0 = floorf(cz);
        const float fx = cx - fx0, fy = cy - fy0, fz = cz - fz0;
        const int ix0 = (int)fx0, iy0 = (int)fy0, iz0 = (int)fz0;
        const int ix1 = min(ix0 + 1, 127);
        const int iy1 = min(iy0 + 1, 127);
        const int iz1 = min(iz0 + 1, 127);

        const float gx0 = 1.0f - fx, gy0 = 1.0f - fy, gz0 = 1.0f - fz;

        const int offs[8] = {
            iz0*(kRes*kRes) + iy0*kRes + ix0,
            iz0*(kRes*kRes) + iy0*kRes + ix1,
            iz0*(kRes*kRes) + iy1*kRes + ix0,
            iz0*(kRes*kRes) + iy1*kRes + ix1,
            iz1*(kRes*kRes) + iy0*kRes + ix0,
            iz1*(kRes*kRes) + iy0*kRes + ix1,
            iz1*(kRes*kRes) + iy1*kRes + ix0,
            iz1*(kRes*kRes) + iy1*kRes + ix1 };
        const float cw[8] = {
            gz0*gy0*gx0, gz0*gy0*fx, gz0*fy*gx0, gz0*fy*fx,
            fz *gy0*gx0, fz *gy0*fx, fz *fy*gx0, fz *fy*fx };

        #pragma unroll
        for (int cn = 0; cn < 8; ++cn) {
            const h8* vp = (const h8*)(vox + (size_t)offs[cn] * kVoxPad);
            const h8 q0 = vp[0], q1 = vp[1], q2 = vp[2], q3 = vp[3];

            float f[28];
            #pragma unroll
            for (int i = 0; i < 8; ++i) f[i]      = (float)q0[i];
            #pragma unroll
            for (int i = 0; i < 8; ++i) f[8 + i]  = (float)q1[i];
            #pragma unroll
            for (int i = 0; i < 8; ++i) f[16 + i] = (float)q2[i];
            #pragma unroll
            for (int i = 0; i < 4; ++i) f[24 + i] = (float)q3[i];

            float r = 0.f, g = 0.f, b = 0.f;
            #pragma unroll
            for (int j = 0; j < 9; ++j) {
                r = fmaf(shm[j], f[j],      r);
                g = fmaf(shm[j], f[9 + j],  g);
                b = fmaf(shm[j], f[18 + j], b);
            }
            const float wc = cw[cn];
            s.rp0 = fmaf(wc, r, s.rp0);
            s.rp1 = fmaf(wc, g, s.rp1);
            s.rp2 = fmaf(wc, b, s.rp2);
            sig   = fmaf(wc, f[27], sig);
        }
        sig = fmaxf(sig, 0.0f);
    }
    s.alpha = 1.0f - expf(-sig * dist);
    s.a     = 1.0f - s.alpha + 1e-10f;
    return s;
}

// ---------------------------------------------------------------------------
// Render one 128-sample chunk of one ray per wave; lane handles samples
// (base+lane) and (base+64+lane).  Emits S_R,S_G,S_B,S_L (unit carry) + P.
// ---------------------------------------------------------------------------
__global__ __launch_bounds__(256, 3)
void render_chunks(const float* __restrict__ rays_o,
                   const float* __restrict__ rays_d,
                   const _Float16* __restrict__ vox,
                   float* __restrict__ partials)           // (4096,4,5)
{
    const int lane  = threadIdx.x & 63;
    const int W     = blockIdx.x * 4 + (threadIdx.x >> 6); // 16384 waves
    const int ray   = W >> 2;
    const int chunk = W & 3;

    const float ox = rays_o[3*ray+0], oy = rays_o[3*ray+1], oz = rays_o[3*ray+2];
    const float dx = rays_d[3*ray+0], dy = rays_d[3*ray+1], dz = rays_d[3*ray+2];

    const float sx = fminf(( kRadius - ox)/dx, (-kRadius - ox)/dx);
    const float sy = fminf(( kRadius - oy)/dy, (-kRadius - oy)/dy);
    const float sz = fminf(( kRadius - oz)/dz, (-kRadius - oz)/dz);
    const float start = fmaxf(sx, fmaxf(sy, sz));
    const float dnorm = sqrtf(dx*dx + dy*dy + dz*dz);
    const float dist  = kStep * dnorm;

    float shm[9];
    shm[0] =  0.28209479177387814f;
    shm[1] = -0.4886025119029199f * dy;
    shm[2] =  0.4886025119029199f * dz;
    shm[3] = -0.4886025119029199f * dx;
    shm[4] =  1.0925484305920792f * dx * dy;
    shm[5] = -1.0925484305920792f * dy * dz;
    shm[6] =  0.31539156525252005f * (2.0f*dz*dz - dx*dx - dy*dy);
    shm[7] = -1.0925484305920792f * dx * dz;
    shm[8] =  0.5462742152960396f * (dx*dx - dy*dy);

    const int base = chunk * 128;
    const Sample A = eval_sample(base + lane,      start, ox, oy, oz, dx, dy, dz, dist, shm, vox);
    const Sample B = eval_sample(base + 64 + lane, start, ox, oy, oz, dx, dy, dz, dist, shm, vox);

    // scan sub-chunk A
    float prodA = A.a;
    #pragma unroll
    for (int off = 1; off < 64; off <<= 1) {
        const float y = __shfl_up(prodA, off, 64);
        if (lane >= off) prodA *= y;
    }
    float exclA = __shfl_up(prodA, 1, 64);
    if (lane == 0) exclA = 1.0f;
    const float P0 = __shfl(prodA, 63, 64);

    // scan sub-chunk B
    float prodB = B.a;
    #pragma unroll
    for (int off = 1; off < 64; off <<= 1) {
        const float y = __shfl_up(prodB, off, 64);
        if (lane >= off) prodB *= y;
    }
    float exclB = __shfl_up(prodB, 1, 64);
    if (lane == 0) exclB = 1.0f;
    const float P1 = __shfl(prodB, 63, 64);

    const float wA = A.alpha * exclA;          // unit-carry abs_light
    const float wB = B.alpha * P0 * exclB;

    float sR = 0.f, sG = 0.f, sB = 0.f;
    if (A.inb) {
        sR = wA * (1.0f / (1.0f + expf(-A.rp0)));
        sG = wA * (1.0f / (1.0f + expf(-A.rp1)));
        sB = wA * (1.0f / (1.0f + expf(-A.rp2)));
    }
    if (B.inb) {
        sR = fmaf(wB, 1.0f / (1.0f + expf(-B.rp0)), sR);
        sG = fmaf(wB, 1.0f / (1.0f + expf(-B.rp1)), sG);
        sB = fmaf(wB, 1.0f / (1.0f + expf(-B.rp2)), sB);
    }
    float sL = wA + wB;
    const float P = P0 * P1;

    #pragma unroll
    for (int off = 32; off > 0; off >>= 1) {
        sR += __shfl_down(sR, off, 64);
        sG += __shfl_down(sG, off, 64);
        sB += __shfl_down(sB, off, 64);
        sL += __shfl_down(sL, off, 64);
    }

    if (lane == 0) {
        float* p = partials + (size_t)(ray * kChunks4 + chunk) * 5;
        p[0] = sR; p[1] = sG; p[2] = sB; p[3] = sL; p[4] = P;
    }
}

// ---------------------------------------------------------------------------
// Stitch chunk partials: acc += carry * S_c ; carry *= P_c.
// ---------------------------------------------------------------------------
__global__ __launch_bounds__(256)
void combine_chunks(const float* __restrict__ partials, float* __restrict__ out)
{
    const int r = blockIdx.x * 256 + threadIdx.x;          // 16 blocks
    const float* p = partials + (size_t)r * (kChunks4 * 5);

    float carry = 1.0f, aR = 0.f, aG = 0.f, aB = 0.f, aL = 0.f;
    #pragma unroll
    for (int c = 0; c < kChunks4; ++c) {
        aR = fmaf(carry, p[c*5 + 0], aR);
        aG = fmaf(carry, p[c*5 + 1], aG);
        aB = fmaf(carry, p[c*5 + 2], aB);
        aL = fmaf(carry, p[c*5 + 3], aL);
        carry *= p[c*5 + 4];
    }
    const float bg = 1.0f - aL;
    out[3*r + 0] = aR + bg;
    out[3*r + 1] = aG + bg;
    out[3*r + 2] = aB + bg;
}

// ---------------------------------------------------------------------------
// Fallback: direct channel-major render (round-1 style) if ws too small.
// ---------------------------------------------------------------------------
#define TRI8(p) (w000*(p)[o000] + w001*(p)[o001] + w010*(p)[o010] + w011*(p)[o011] \
               + w100*(p)[o100] + w101*(p)[o101] + w110*(p)[o110] + w111*(p)[o111])

__global__ __launch_bounds__(256)
void plenoxel_render_direct(const float* __restrict__ rays_o,
                            const float* __restrict__ rays_d,
                            const float* __restrict__ grid,
                            float* __restrict__ out)
{
    const int lane = threadIdx.x & 63;
    const int ray  = blockIdx.x * 4 + (threadIdx.x >> 6);

    const float ox = rays_o[3*ray+0], oy = rays_o[3*ray+1], oz = rays_o[3*ray+2];
    const float dx = rays_d[3*ray+0], dy = rays_d[3*ray+1], dz = rays_d[3*ray+2];

    const float sx = fminf(( kRadius - ox)/dx, (-kRadius - ox)/dx);
    const float sy = fminf(( kRadius - oy)/dy, (-kRadius - oy)/dy);
    const float sz = fminf(( kRadius - oz)/dz, (-kRadius - oz)/dz);
    const float start = fmaxf(sx, fmaxf(sy, sz));
    const float dnorm = sqrtf(dx*dx + dy*dy + dz*dz);

    float shm[9];
    shm[0] =  0.28209479177387814f;
    shm[1] = -0.4886025119029199f * dy;
    shm[2] =  0.4886025119029199f * dz;
    shm[3] = -0.4886025119029199f * dx;
    shm[4] =  1.0925484305920792f * dx * dy;
    shm[5] = -1.0925484305920792f * dy * dz;
    shm[6] =  0.31539156525252005f * (2.0f*dz*dz - dx*dx - dy*dy);
    shm[7] = -1.0925484305920792f * dx * dz;
    shm[8] =  0.5462742152960396f * (dx*dx - dy*dy);

    float carry = 1.0f;
    float accR = 0.f, accG = 0.f, accB = 0.f, accL = 0.f;

    for (int chunk = 0; chunk < kChunks7; ++chunk) {
        const int k = chunk * 64 + lane;
        float alpha = 0.0f, a = 1.0f;
        float rp0 = 0.f, rp1 = 0.f, rp2 = 0.f;
        bool inb = false;

        if (k < kNI) {
            const float t = start + (float)k * kStep;
            const float dist = kStep * dnorm;
            const float px = ox + t*dx, py = oy + t*dy, pz = oz + t*dz;
            inb = (px > -kRadius) && (px < kRadius) &&
                  (py > -kRadius) && (py < kRadius) &&
                  (pz > -kRadius) && (pz < kRadius);
            float sigma = 0.0f;
            if (inb) {
                const float cx = fminf(fmaxf((px*(1.0f/kRadius) + 1.0f)*0.5f*127.0f, 0.0f), 127.0f);
                const float cy = fminf(fmaxf((py*(1.0f/kRadius) + 1.0f)*0.5f*127.0f, 0.0f), 127.0f);
                const float cz = fminf(fmaxf((pz*(1.0f/kRadius) + 1.0f)*0.5f*127.0f, 0.0f), 127.0f);
                const float fx0 = floorf(cx), fy0 = floorf(cy), fz0 = floorf(cz);
                const float fx = cx - fx0, fy = cy - fy0, fz = cz - fz0;
                const int ix0 = (int)fx0, iy0 = (int)fy0, iz0 = (int)fz0;
                const int ix1 = min(ix0 + 1, 127);
                const int iy1 = min(iy0 + 1, 127);
                const int iz1 = min(iz0 + 1, 127);
                const float gx0 = 1.0f - fx, gy0 = 1.0f - fy, gz0 = 1.0f - fz;
                const float w000 = gz0*gy0*gx0, w001 = gz0*gy0*fx;
                const float w010 = gz0*fy *gx0, w011 = gz0*fy *fx;
                const float w100 = fz *gy0*gx0, w101 = fz *gy0*fx;
                const float w110 = fz *fy *gx0, w111 = fz *fy *fx;
                const int o000 = iz0*(kRes*kRes) + iy0*kRes + ix0;
                const int o001 = iz0*(kRes*kRes) + iy0*kRes + ix1;
                const int o010 = iz0*(kRes*kRes) + iy1*kRes + ix0;
                const int o011 = iz0*(kRes*kRes) + iy1*kRes + ix1;
                const int o100 = iz1*(kRes*kRes) + iy0*kRes + ix0;
                const int o101 = iz1*(kRes*kRes) + iy0*kRes + ix1;
                const int o110 = iz1*(kRes*kRes) + iy1*kRes + ix0;
                const int o111 = iz1*(kRes*kRes) + iy1*kRes + ix1;
                #pragma unroll
                for (int kk = 0; kk < 9; ++kk) {
                    rp0 = fmaf(shm[kk], TRI8(grid + (kk     ) * kChStride), rp0);
                    rp1 = fmaf(shm[kk], TRI8(grid + (kk +  9) * kChStride), rp1);
                    rp2 = fmaf(shm[kk], TRI8(grid + (kk + 18) * kChStride), rp2);
                }
                sigma = fmaxf(TRI8(grid + 27 * kChStride), 0.0f);
            }
            alpha = 1.0f - expf(-sigma * dist);
            a     = 1.0f - alpha + 1e-10f;
        }

        float prod = a;
        #pragma unroll
        for (int off = 1; off < 64; off <<= 1) {
            const float y = __shfl_up(prod, off, 64);
            if (lane >= off) prod *= y;
        }
        float excl = __shfl_up(prod, 1, 64);
        if (lane == 0) excl = 1.0f;
        const float trans = carry * excl;
        const float w = alpha * trans;
        if (inb) {
            accR = fmaf(w, 1.0f / (1.0f + expf(-rp0)), accR);
            accG = fmaf(w, 1.0f / (1.0f + expf(-rp1)), accG);
            accB = fmaf(w, 1.0f / (1.0f + expf(-rp2)), accB);
        }
        accL += w;
        carry *= __shfl(prod, 63, 64);
    }

    #pragma unroll
    for (int off = 32; off > 0; off >>= 1) {
        accR += __shfl_down(accR, off, 64);
        accG += __shfl_down(accG, off, 64);
        accB += __shfl_down(accB, off, 64);
        accL += __shfl_down(accL, off, 64);
    }

    if (lane == 0) {
        const float bg = 1.0f - accL;
        out[3*ray + 0] = accR + bg;
        out[3*ray + 1] = accG + bg;
        out[3*ray + 2] = accB + bg;
    }
}

extern "C" void kernel_launch(void* const* d_in, const int* in_sizes, int n_in,
                              void* d_out, int out_size, void* d_ws, size_t ws_size,
                              hipStream_t stream) {
    const float* rays_o = (const float*)d_in[0];
    const float* rays_d = (const float*)d_in[1];
    const float* data   = (const float*)d_in[2];   // (1,28,128,128,128)
    float* out = (float*)d_out;

    const size_t partBytes = (size_t)kNRays * kChunks4 * 5 * sizeof(float);
    const size_t need = kVoxBytes + partBytes;     // ~134.5 MB

    if (ws_size >= need) {
        _Float16* vox = (_Float16*)d_ws;
        float* partials = (float*)((char*)d_ws + kVoxBytes);

        hipLaunchKernelGGL(convert_grid,
                           dim3(kChStride / 256), dim3(256), 0, stream,
                           data, vox);
        hipLaunchKernelGGL(render_chunks,
                           dim3(kNRays * kChunks4 / 4), dim3(256), 0, stream,
                           rays_o, rays_d, vox, partials);
        hipLaunchKernelGGL(combine_chunks,
                           dim3(kNRays / 256), dim3(256), 0, stream,
                           partials, out);
    } else {
        hipLaunchKernelGGL(plenoxel_render_direct,
                           dim3(kNRays / 4), dim3(256), 0, stream,
                           rays_o, rays_d, data, out);
    }
}

// Round 5
// 393.696 us; speedup vs baseline: 2.7273x; 1.0250x over previous
//
#include <hip/hip_runtime.h>
#include <math.h>

// Plenoxels renderer, round 5.
//  - fp16 voxel-major 64B records (one cacheline/voxel), 134MB, L3-resident.
//  - render: 4 samples per lane (k, k+64, k+128, k+192) in 256-sample chunks
//    -> 4x per-wave gather MLP; 8192 waves.
//  - whole-wave early exit when the chunk starts beyond the ray's box exit.

typedef _Float16 h8 __attribute__((ext_vector_type(8)));

namespace {
constexpr float kRadius   = 1.3f;
constexpr int   kRes      = 128;
constexpr float kStep     = 2.0f * 1.3f / 128.0f / 2.0f;   // 0.01015625
constexpr int   kNI       = 443;                           // N_INTRS - 1
constexpr int   kNRays    = 4096;
constexpr int   kChStride = kRes * kRes * kRes;            // 2097152 voxels
constexpr int   kCh       = 28;
constexpr int   kVoxPad   = 32;                            // halves per 64B record
constexpr size_t kVoxBytes = (size_t)kChStride * kVoxPad * sizeof(_Float16);
constexpr int   kChunks   = 2;                             // 256-sample chunks
constexpr int   kChunks7  = 7;                             // fallback: 64-sample
}

// ---------------------------------------------------------------------------
// Convert grid[c][v] (f32 channel-major) -> vox[v] = 32 halves (64B record).
// ---------------------------------------------------------------------------
__global__ __launch_bounds__(256)
void convert_grid(const float* __restrict__ grid, _Float16* __restrict__ vox)
{
    const int v = blockIdx.x * 256 + threadIdx.x;          // 8192 blocks
    h8 o[4];
    #pragma unroll
    for (int c = 0; c < kCh; ++c)
        o[c >> 3][c & 7] = (_Float16)__builtin_nontemporal_load(grid + (size_t)c * kChStride + v);
    o[3][4] = o[3][5] = o[3][6] = o[3][7] = (_Float16)0.f;

    h8* dst = (h8*)(vox + (size_t)v * kVoxPad);
    dst[0] = o[0]; dst[1] = o[1]; dst[2] = o[2]; dst[3] = o[3];
}

// ---------------------------------------------------------------------------
// Per-sample evaluation: trilerped sigma->alpha and SH-dot rgb logits.
// ---------------------------------------------------------------------------
struct Sample {
    float alpha;   // 1 - exp(-sigma*dist)
    float a;       // 1 - alpha + 1e-10
    float rp0, rp1, rp2;
    bool  inb;
};

__device__ __forceinline__ Sample eval_sample(
    int k, float start, float ox, float oy, float oz,
    float dx, float dy, float dz, float dist,
    const float* __restrict__ shm, const _Float16* __restrict__ vox)
{
    Sample s;
    s.alpha = 0.f; s.a = 1.f; s.rp0 = s.rp1 = s.rp2 = 0.f; s.inb = false;
    if (k >= kNI) return s;

    const float t  = start + (float)k * kStep;
    const float px = ox + t*dx;
    const float py = oy + t*dy;
    const float pz = oz + t*dz;
    s.inb = (px > -kRadius) && (px < kRadius) &&
            (py > -kRadius) && (py < kRadius) &&
            (pz > -kRadius) && (pz < kRadius);

    float sig = 0.0f;
    if (s.inb) {
        const float cx = fminf(fmaxf((px*(1.0f/kRadius) + 1.0f)*0.5f*127.0f, 0.0f), 127.0f);
        const float cy = fminf(fmaxf((py*(1.0f/kRadius) + 1.0f)*0.5f*127.0f, 0.0f), 127.0f);
        const float cz = fminf(fmaxf((pz*(1.0f/kRadius) + 1.0f)*0.5f*127.0f, 0.0f), 127.0f);
        const float fx0 = floorf(cx), fy0 = floorf(cy), fz0 = floorf(cz);
        const float fx = cx - fx0, fy = cy - fy0, fz = cz - fz0;
        const int ix0 = (int)fx0, iy0 = (int)fy0, iz0 = (int)fz0;
        const int ix1 = min(ix0 + 1, 127);
        const int iy1 = min(iy0 + 1, 127);
        const int iz1 = min(iz0 + 1, 127);

        const float gx0 = 1.0f - fx, gy0 = 1.0f - fy, gz0 = 1.0f - fz;

        const int offs[8] = {
            iz0*(kRes*kRes) + iy0*kRes + ix0,
            iz0*(kRes*kRes) + iy0*kRes + ix1,
            iz0*(kRes*kRes) + iy1*kRes + ix0,
            iz0*(kRes*kRes) + iy1*kRes + ix1,
            iz1*(kRes*kRes) + iy0*kRes + ix0,
            iz1*(kRes*kRes) + iy0*kRes + ix1,
            iz1*(kRes*kRes) + iy1*kRes + ix0,
            iz1*(kRes*kRes) + iy1*kRes + ix1 };
        const float cw[8] = {
            gz0*gy0*gx0, gz0*gy0*fx, gz0*fy*gx0, gz0*fy*fx,
            fz *gy0*gx0, fz *gy0*fx, fz *fy*gx0, fz *fy*fx };

        #pragma unroll
        for (int cn = 0; cn < 8; ++cn) {
            const h8* vp = (const h8*)(vox + (size_t)offs[cn] * kVoxPad);
            const h8 q0 = vp[0], q1 = vp[1], q2 = vp[2], q3 = vp[3];

            float f[28];
            #pragma unroll
            for (int i = 0; i < 8; ++i) f[i]      = (float)q0[i];
            #pragma unroll
            for (int i = 0; i < 8; ++i) f[8 + i]  = (float)q1[i];
            #pragma unroll
            for (int i = 0; i < 8; ++i) f[16 + i] = (float)q2[i];
            #pragma unroll
            for (int i = 0; i < 4; ++i) f[24 + i] = (float)q3[i];

            float r = 0.f, g = 0.f, b = 0.f;
            #pragma unroll
            for (int j = 0; j < 9; ++j) {
                r = fmaf(shm[j], f[j],      r);
                g = fmaf(shm[j], f[9 + j],  g);
                b = fmaf(shm[j], f[18 + j], b);
            }
            const float wc = cw[cn];
            s.rp0 = fmaf(wc, r, s.rp0);
            s.rp1 = fmaf(wc, g, s.rp1);
            s.rp2 = fmaf(wc, b, s.rp2);
            sig   = fmaf(wc, f[27], sig);
        }
        sig = fmaxf(sig, 0.0f);
    }
    s.alpha = 1.0f - expf(-sig * dist);
    s.a     = 1.0f - s.alpha + 1e-10f;
    return s;
}

__device__ __forceinline__ float wave_scan_prod(float a, int lane, float& total)
{
    float prod = a;
    #pragma unroll
    for (int off = 1; off < 64; off <<= 1) {
        const float y = __shfl_up(prod, off, 64);
        if (lane >= off) prod *= y;
    }
    float excl = __shfl_up(prod, 1, 64);
    if (lane == 0) excl = 1.0f;
    total = __shfl(prod, 63, 64);
    return excl;
}

// ---------------------------------------------------------------------------
// Render one 256-sample chunk of one ray per wave; lane handles samples
// base+lane+{0,64,128,192}.  Emits S_R,S_G,S_B,S_L (unit carry) + P.
// ---------------------------------------------------------------------------
__global__ __launch_bounds__(256, 3)
void render_chunks(const float* __restrict__ rays_o,
                   const float* __restrict__ rays_d,
                   const _Float16* __restrict__ vox,
                   float* __restrict__ partials)           // (4096,2,5)
{
    const int lane  = threadIdx.x & 63;
    const int W     = blockIdx.x * 4 + (threadIdx.x >> 6); // 8192 waves
    const int ray   = W >> 1;
    const int chunk = W & 1;

    const float ox = rays_o[3*ray+0], oy = rays_o[3*ray+1], oz = rays_o[3*ray+2];
    const float dx = rays_d[3*ray+0], dy = rays_d[3*ray+1], dz = rays_d[3*ray+2];

    const float ppx = ( kRadius - ox)/dx, pnx = (-kRadius - ox)/dx;
    const float ppy = ( kRadius - oy)/dy, pny = (-kRadius - oy)/dy;
    const float ppz = ( kRadius - oz)/dz, pnz = (-kRadius - oz)/dz;
    const float start  = fmaxf(fminf(ppx, pnx), fmaxf(fminf(ppy, pny), fminf(ppz, pnz)));
    const float t_exit = fminf(fmaxf(ppx, pnx), fminf(fmaxf(ppy, pny), fmaxf(ppz, pnz)));

    const int base = chunk * 256;

    // whole-wave early exit: first sample of this chunk already past box exit
    // (margin of one step absorbs any fp rounding; mask is strict-inside anyway)
    if (start + (float)base * kStep > t_exit + kStep) {
        if (lane == 0) {
            float* p = partials + (size_t)(ray * kChunks + chunk) * 5;
            p[0] = 0.f; p[1] = 0.f; p[2] = 0.f; p[3] = 0.f; p[4] = 1.f;
        }
        return;
    }

    const float dnorm = sqrtf(dx*dx + dy*dy + dz*dz);
    const float dist  = kStep * dnorm;

    float shm[9];
    shm[0] =  0.28209479177387814f;
    shm[1] = -0.4886025119029199f * dy;
    shm[2] =  0.4886025119029199f * dz;
    shm[3] = -0.4886025119029199f * dx;
    shm[4] =  1.0925484305920792f * dx * dy;
    shm[5] = -1.0925484305920792f * dy * dz;
    shm[6] =  0.31539156525252005f * (2.0f*dz*dz - dx*dx - dy*dy);
    shm[7] = -1.0925484305920792f * dx * dz;
    shm[8] =  0.5462742152960396f * (dx*dx - dy*dy);

    const Sample A = eval_sample(base       + lane, start, ox, oy, oz, dx, dy, dz, dist, shm, vox);
    const Sample B = eval_sample(base +  64 + lane, start, ox, oy, oz, dx, dy, dz, dist, shm, vox);
    const Sample C = eval_sample(base + 128 + lane, start, ox, oy, oz, dx, dy, dz, dist, shm, vox);
    const Sample D = eval_sample(base + 192 + lane, start, ox, oy, oz, dx, dy, dz, dist, shm, vox);

    float P0, P1, P2, P3;
    const float eA = wave_scan_prod(A.a, lane, P0);
    const float eB = wave_scan_prod(B.a, lane, P1);
    const float eC = wave_scan_prod(C.a, lane, P2);
    const float eD = wave_scan_prod(D.a, lane, P3);

    const float wA = A.alpha * eA;
    const float wB = B.alpha * P0 * eB;
    const float wC = C.alpha * P0 * P1 * eC;
    const float wD = D.alpha * P0 * P1 * P2 * eD;

    float sR = 0.f, sG = 0.f, sB = 0.f;
    if (A.inb) {
        sR = wA * (1.0f / (1.0f + expf(-A.rp0)));
        sG = wA * (1.0f / (1.0f + expf(-A.rp1)));
        sB = wA * (1.0f / (1.0f + expf(-A.rp2)));
    }
    if (B.inb) {
        sR = fmaf(wB, 1.0f / (1.0f + expf(-B.rp0)), sR);
        sG = fmaf(wB, 1.0f / (1.0f + expf(-B.rp1)), sG);
        sB = fmaf(wB, 1.0f / (1.0f + expf(-B.rp2)), sB);
    }
    if (C.inb) {
        sR = fmaf(wC, 1.0f / (1.0f + expf(-C.rp0)), sR);
        sG = fmaf(wC, 1.0f / (1.0f + expf(-C.rp1)), sG);
        sB = fmaf(wC, 1.0f / (1.0f + expf(-C.rp2)), sB);
    }
    if (D.inb) {
        sR = fmaf(wD, 1.0f / (1.0f + expf(-D.rp0)), sR);
        sG = fmaf(wD, 1.0f / (1.0f + expf(-D.rp1)), sG);
        sB = fmaf(wD, 1.0f / (1.0f + expf(-D.rp2)), sB);
    }
    float sL = wA + wB + wC + wD;
    const float P = P0 * P1 * P2 * P3;

    #pragma unroll
    for (int off = 32; off > 0; off >>= 1) {
        sR += __shfl_down(sR, off, 64);
        sG += __shfl_down(sG, off, 64);
        sB += __shfl_down(sB, off, 64);
        sL += __shfl_down(sL, off, 64);
    }

    if (lane == 0) {
        float* p = partials + (size_t)(ray * kChunks + chunk) * 5;
        p[0] = sR; p[1] = sG; p[2] = sB; p[3] = sL; p[4] = P;
    }
}

// ---------------------------------------------------------------------------
// Stitch chunk partials: acc += carry * S_c ; carry *= P_c.
// ---------------------------------------------------------------------------
__global__ __launch_bounds__(256)
void combine_chunks(const float* __restrict__ partials, float* __restrict__ out)
{
    const int r = blockIdx.x * 256 + threadIdx.x;          // 16 blocks
    const float* p = partials + (size_t)r * (kChunks * 5);

    float carry = 1.0f, aR = 0.f, aG = 0.f, aB = 0.f, aL = 0.f;
    #pragma unroll
    for (int c = 0; c < kChunks; ++c) {
        aR = fmaf(carry, p[c*5 + 0], aR);
        aG = fmaf(carry, p[c*5 + 1], aG);
        aB = fmaf(carry, p[c*5 + 2], aB);
        aL = fmaf(carry, p[c*5 + 3], aL);
        carry *= p[c*5 + 4];
    }
    const float bg = 1.0f - aL;
    out[3*r + 0] = aR + bg;
    out[3*r + 1] = aG + bg;
    out[3*r + 2] = aB + bg;
}

// ---------------------------------------------------------------------------
// Fallback: direct channel-major render (round-1 style) if ws too small.
// ---------------------------------------------------------------------------
#define TRI8(p) (w000*(p)[o000] + w001*(p)[o001] + w010*(p)[o010] + w011*(p)[o011] \
               + w100*(p)[o100] + w101*(p)[o101] + w110*(p)[o110] + w111*(p)[o111])

__global__ __launch_bounds__(256)
void plenoxel_render_direct(const float* __restrict__ rays_o,
                            const float* __restrict__ rays_d,
                            const float* __restrict__ grid,
                            float* __restrict__ out)
{
    const int lane = threadIdx.x & 63;
    const int ray  = blockIdx.x * 4 + (threadIdx.x >> 6);

    const float ox = rays_o[3*ray+0], oy = rays_o[3*ray+1], oz = rays_o[3*ray+2];
    const float dx = rays_d[3*ray+0], dy = rays_d[3*ray+1], dz = rays_d[3*ray+2];

    const float sx = fminf(( kRadius - ox)/dx, (-kRadius - ox)/dx);
    const float sy = fminf(( kRadius - oy)/dy, (-kRadius - oy)/dy);
    const float sz = fminf(( kRadius - oz)/dz, (-kRadius - oz)/dz);
    const float start = fmaxf(sx, fmaxf(sy, sz));
    const float dnorm = sqrtf(dx*dx + dy*dy + dz*dz);

    float shm[9];
    shm[0] =  0.28209479177387814f;
    shm[1] = -0.4886025119029199f * dy;
    shm[2] =  0.4886025119029199f * dz;
    shm[3] = -0.4886025119029199f * dx;
    shm[4] =  1.0925484305920792f * dx * dy;
    shm[5] = -1.0925484305920792f * dy * dz;
    shm[6] =  0.31539156525252005f * (2.0f*dz*dz - dx*dx - dy*dy);
    shm[7] = -1.0925484305920792f * dx * dz;
    shm[8] =  0.5462742152960396f * (dx*dx - dy*dy);

    float carry = 1.0f;
    float accR = 0.f, accG = 0.f, accB = 0.f, accL = 0.f;

    for (int chunk = 0; chunk < kChunks7; ++chunk) {
        const int k = chunk * 64 + lane;
        float alpha = 0.0f, a = 1.0f;
        float rp0 = 0.f, rp1 = 0.f, rp2 = 0.f;
        bool inb = false;

        if (k < kNI) {
            const float t = start + (float)k * kStep;
            const float dist = kStep * dnorm;
            const float px = ox + t*dx, py = oy + t*dy, pz = oz + t*dz;
            inb = (px > -kRadius) && (px < kRadius) &&
                  (py > -kRadius) && (py < kRadius) &&
                  (pz > -kRadius) && (pz < kRadius);
            float sigma = 0.0f;
            if (inb) {
                const float cx = fminf(fmaxf((px*(1.0f/kRadius) + 1.0f)*0.5f*127.0f, 0.0f), 127.0f);
                const float cy = fminf(fmaxf((py*(1.0f/kRadius) + 1.0f)*0.5f*127.0f, 0.0f), 127.0f);
                const float cz = fminf(fmaxf((pz*(1.0f/kRadius) + 1.0f)*0.5f*127.0f, 0.0f), 127.0f);
                const float fx0 = floorf(cx), fy0 = floorf(cy), fz0 = floorf(cz);
                const float fx = cx - fx0, fy = cy - fy0, fz = cz - fz0;
                const int ix0 = (int)fx0, iy0 = (int)fy0, iz0 = (int)fz0;
                const int ix1 = min(ix0 + 1, 127);
                const int iy1 = min(iy0 + 1, 127);
                const int iz1 = min(iz0 + 1, 127);
                const float gx0 = 1.0f - fx, gy0 = 1.0f - fy, gz0 = 1.0f - fz;
                const float w000 = gz0*gy0*gx0, w001 = gz0*gy0*fx;
                const float w010 = gz0*fy *gx0, w011 = gz0*fy *fx;
                const float w100 = fz *gy0*gx0, w101 = fz *gy0*fx;
                const float w110 = fz *fy *gx0, w111 = fz *fy *fx;
                const int o000 = iz0*(kRes*kRes) + iy0*kRes + ix0;
                const int o001 = iz0*(kRes*kRes) + iy0*kRes + ix1;
                const int o010 = iz0*(kRes*kRes) + iy1*kRes + ix0;
                const int o011 = iz0*(kRes*kRes) + iy1*kRes + ix1;
                const int o100 = iz1*(kRes*kRes) + iy0*kRes + ix0;
                const int o101 = iz1*(kRes*kRes) + iy0*kRes + ix1;
                const int o110 = iz1*(kRes*kRes) + iy1*kRes + ix0;
                const int o111 = iz1*(kRes*kRes) + iy1*kRes + ix1;
                #pragma unroll
                for (int kk = 0; kk < 9; ++kk) {
                    rp0 = fmaf(shm[kk], TRI8(grid + (kk     ) * kChStride), rp0);
                    rp1 = fmaf(shm[kk], TRI8(grid + (kk +  9) * kChStride), rp1);
                    rp2 = fmaf(shm[kk], TRI8(grid + (kk + 18) * kChStride), rp2);
                }
                sigma = fmaxf(TRI8(grid + 27 * kChStride), 0.0f);
            }
            alpha = 1.0f - expf(-sigma * dist);
            a     = 1.0f - alpha + 1e-10f;
        }

        float prod = a;
        #pragma unroll
        for (int off = 1; off < 64; off <<= 1) {
            const float y = __shfl_up(prod, off, 64);
            if (lane >= off) prod *= y;
        }
        float excl = __shfl_up(prod, 1, 64);
        if (lane == 0) excl = 1.0f;
        const float trans = carry * excl;
        const float w = alpha * trans;
        if (inb) {
            accR = fmaf(w, 1.0f / (1.0f + expf(-rp0)), accR);
            accG = fmaf(w, 1.0f / (1.0f + expf(-rp1)), accG);
            accB = fmaf(w, 1.0f / (1.0f + expf(-rp2)), accB);
        }
        accL += w;
        carry *= __shfl(prod, 63, 64);
    }

    #pragma unroll
    for (int off = 32; off > 0; off >>= 1) {
        accR += __shfl_down(accR, off, 64);
        accG += __shfl_down(accG, off, 64);
        accB += __shfl_down(accB, off, 64);
        accL += __shfl_down(accL, off, 64);
    }

    if (lane == 0) {
        const float bg = 1.0f - accL;
        out[3*ray + 0] = accR + bg;
        out[3*ray + 1] = accG + bg;
        out[3*ray + 2] = accB + bg;
    }
}

extern "C" void kernel_launch(void* const* d_in, const int* in_sizes, int n_in,
                              void* d_out, int out_size, void* d_ws, size_t ws_size,
                              hipStream_t stream) {
    const float* rays_o = (const float*)d_in[0];
    const float* rays_d = (const float*)d_in[1];
    const float* data   = (const float*)d_in[2];   // (1,28,128,128,128)
    float* out = (float*)d_out;

    const size_t partBytes = (size_t)kNRays * kChunks * 5 * sizeof(float);
    const size_t need = kVoxBytes + partBytes;     // ~134.3 MB

    if (ws_size >= need) {
        _Float16* vox = (_Float16*)d_ws;
        float* partials = (float*)((char*)d_ws + kVoxBytes);

        hipLaunchKernelGGL(convert_grid,
                           dim3(kChStride / 256), dim3(256), 0, stream,
                           data, vox);
        hipLaunchKernelGGL(render_chunks,
                           dim3(kNRays * kChunks / 4), dim3(256), 0, stream,
                           rays_o, rays_d, vox, partials);
        hipLaunchKernelGGL(combine_chunks,
                           dim3(kNRays / 256), dim3(256), 0, stream,
                           partials, out);
    } else {
        hipLaunchKernelGGL(plenoxel_render_direct,
                           dim3(kNRays / 4), dim3(256), 0, stream,
                           rays_o, rays_d, data, out);
    }
}